// Round 18
// baseline (204.179 us; speedup 1.0000x reference)
//
#include <hip/hip_runtime.h>

// 2-layer GCN: h = relu(Anorm @ (x@W1) + b1); out = relu(Anorm @ (h@W2) + b2)
// Round 18: column-blocked gathers. h1 stored as 4 planes [N][32]bf16 (3.2MB,
// fits per-XCD L2), gather1 runs as 4 pass-partitioned block ranges so random
// row-gathers become L2 hits. h2 = 2 planes, gather2 = 2 passes. Mega = R16's
// proven form with plane-directed C-writes.

constexpr int IN_DIM = 512;
constexpr int HD1 = 128;
constexpr int HD2 = 64;

typedef __attribute__((ext_vector_type(8))) short bf16x8;
typedef __attribute__((ext_vector_type(8))) unsigned short u16x8;
typedef __attribute__((ext_vector_type(4))) float f32x4;
typedef unsigned int u32;

__device__ inline unsigned short f2bf(float f) {
    u32 u = __builtin_bit_cast(u32, f);
    return (unsigned short)((u + 0x7fffu + ((u >> 16) & 1u)) >> 16);
}
__device__ inline float bf_lo(u32 v) { return __builtin_bit_cast(float, v << 16); }
__device__ inline float bf_hi(u32 v) { return __builtin_bit_cast(float, v & 0xffff0000u); }

// swizzled LDS element offset, [row][64] bf16 tiles
__device__ inline int elem_off(int row, int k) {
    return (row << 6) + (k ^ ((row & 7) << 3));
}
// swizzled LDS element offset, [row][128] bf16 tiles (gemm2)
__device__ inline int elem_off128(int row, int k) {
    return (row << 7) + (k ^ ((row & 7) << 3));
}

// ---------- zero deg ----------
__global__ __launch_bounds__(256) void k_zero(int* __restrict__ deg, int N) {
    int i = blockIdx.x * 256 + threadIdx.x;
    if (i < N) deg[i] = 0;
}

// ---------- fused prep: deg atomics (rank captured) + W1^T bf16 + W2^T bf16 ----------
__global__ __launch_bounds__(256) void k_prep(const int* __restrict__ dst, int E,
                                              int* __restrict__ deg,
                                              int* __restrict__ rank,
                                              const float* __restrict__ W1,
                                              unsigned short* __restrict__ Wt,
                                              const float* __restrict__ W2,
                                              unsigned short* __restrict__ Wt2) {
    int id = blockIdx.x * 256 + threadIdx.x;
    if (id < E) rank[id] = atomicAdd(&deg[dst[id]], 1);
    if (id < IN_DIM * HD1) {                    // 65536: W1^T
        int n = id >> 9, k = id & 511;
        Wt[id] = f2bf(W1[k * HD1 + n]);
    }
    if (id < HD1 * HD2) {                       // 8192: W2^T
        int n = id >> 7, k = id & 127;
        Wt2[id] = f2bf(W2[k * HD2 + n]);
    }
}

// ---------- dinv + per-block degree sums (fused) ----------
__global__ __launch_bounds__(256) void k_dinv_bsum(const int* __restrict__ deg, int N,
                                                   float* __restrict__ dinv,
                                                   int* __restrict__ bsum) {
    __shared__ int s[256];
    int t = threadIdx.x;
    int i = blockIdx.x * 256 + t;
    int d = (i < N) ? deg[i] : 0;
    if (i < N) dinv[i] = rsqrtf((float)(d + 1));  // +1 = self loop
    s[t] = d;
    __syncthreads();
    for (int st = 128; st > 0; st >>= 1) {
        if (t < st) s[t] += s[t + st];
        __syncthreads();
    }
    if (t == 0) bsum[blockIdx.x] = s[0];
}

// ---------- scan_final with fused bsum scan (nb <= 256) ----------
__global__ __launch_bounds__(256) void k_scan_final(const int* __restrict__ deg, int N,
                                                    const int* __restrict__ bsum, int nb,
                                                    int* __restrict__ rowptr) {
    __shared__ int sb[256];
    __shared__ int s[256];
    int t = threadIdx.x;
    sb[t] = (t < nb) ? bsum[t] : 0;
    __syncthreads();
    for (int off = 1; off < 256; off <<= 1) {
        int v = (t >= off) ? sb[t - off] : 0;
        __syncthreads();
        sb[t] += v;
        __syncthreads();
    }
    int base = (blockIdx.x == 0) ? 0 : sb[blockIdx.x - 1];

    int i = blockIdx.x * 256 + t;
    int v = (i < N) ? deg[i] : 0;
    s[t] = v;
    __syncthreads();
    for (int off = 1; off < 256; off <<= 1) {
        int u = (t >= off) ? s[t - off] : 0;
        __syncthreads();
        s[t] += u;
        __syncthreads();
    }
    int incl = s[t] + base;
    if (i < N) rowptr[i] = incl - v;
    if (i == N - 1) rowptr[N] = incl;
}

// ---------- MEGA: blocks [0,gemmBlocks) = gemm1 (32-row tiles); rest = fill ----------
// C-write goes to 4 column planes h1[p][N][32] (p = gcol>>5).
__global__ __launch_bounds__(256) void k_mega(const float* __restrict__ X,
                                              const unsigned short* __restrict__ Wt,
                                              unsigned short* __restrict__ H, int N,
                                              int gemmBlocks,
                                              const int* __restrict__ src,
                                              const int* __restrict__ dst, int E,
                                              const int* __restrict__ rowptr,
                                              const int* __restrict__ rank,
                                              int* __restrict__ col) {
    __shared__ unsigned short As[32 * 64];    // x tile, swizzled [row][k], 4 KB
    __shared__ unsigned short Bs[128 * 64];   // W tile, swizzled [col][k], 16 KB

    if (blockIdx.x >= gemmBlocks) {
        // ---- CSR fill, atomic-free ----
        const int T = (gridDim.x - gemmBlocks) * 256;
        for (int e = (blockIdx.x - gemmBlocks) * 256 + threadIdx.x; e < E; e += T) {
            int d = dst[e];
            col[rowptr[d] + rank[e]] = src[e];
        }
        return;
    }

    // ---------------- GEMM1: 32 rows x 128 cols per block ----------------
    const int tid = threadIdx.x;
    const int lane = tid & 63;
    const int wid = tid >> 6;
    const int brow = blockIdx.x * 32;
    const int wr0 = (wid >> 1) * 16;          // wave rows: 0 or 16
    const int wc0 = (wid & 1) * 64;           // wave cols: 0 or 64
    const bool full = (brow + 32 <= N);

    f32x4 acc[4];
#pragma unroll
    for (int j = 0; j < 4; j++) acc[j] = (f32x4){0.f, 0.f, 0.f, 0.f};

    for (int kt = 0; kt < IN_DIM / 64; kt++) {
        const int k0 = kt * 64;
        // ---- issue B: global_load_lds, pre-swizzled source ----
#pragma unroll
        for (int p = 0; p < 4; p++) {
            int chunk = (wid * 4 + p) * 64 + lane;  // 16B chunk id
            int n = chunk >> 3;
            int kcs = chunk & 7;
            int kc = kcs ^ (n & 7);                 // inverse swizzle on source
            const unsigned short* srcp = &Wt[(size_t)n * IN_DIM + k0 + kc * 8];
            unsigned short* dstp = &Bs[(wid * 4 + p) * 512];
            __builtin_amdgcn_global_load_lds(
                (const __attribute__((address_space(1))) u32*)(const void*)srcp,
                (__attribute__((address_space(3))) u32*)(void*)dstp, 16, 0, 0);
        }
        // ---- stage A: 32 rows x 64 k, one 8-elem chunk per thread ----
        {
            int r = tid >> 3;
            int kc = tid & 7;
            const float* xp = &X[(size_t)(brow + r) * IN_DIM + k0 + kc * 8];
            float4 v0, v1;
            if (full || (brow + r) < N) {
                v0 = *(const float4*)xp;
                v1 = *(const float4*)(xp + 4);
            } else {
                v0 = make_float4(0.f, 0.f, 0.f, 0.f); v1 = v0;
            }
            u16x8 w;
            w[0] = f2bf(v0.x); w[1] = f2bf(v0.y); w[2] = f2bf(v0.z); w[3] = f2bf(v0.w);
            w[4] = f2bf(v1.x); w[5] = f2bf(v1.y); w[6] = f2bf(v1.z); w[7] = f2bf(v1.w);
            *(u16x8*)&As[elem_off(r, kc * 8)] = w;
        }
        __syncthreads();

#pragma unroll
        for (int kk = 0; kk < 2; kk++) {
            const int kel = kk * 32 + (lane >> 4) * 8;
            bf16x8 a = *(const bf16x8*)&As[elem_off(wr0 + (lane & 15), kel)];
            bf16x8 b[4];
#pragma unroll
            for (int ni = 0; ni < 4; ni++)
                b[ni] = *(const bf16x8*)&Bs[elem_off(wc0 + ni * 16 + (lane & 15), kel)];
#pragma unroll
            for (int ni = 0; ni < 4; ni++)
                acc[ni] = __builtin_amdgcn_mfma_f32_16x16x32_bf16(a, b[ni], acc[ni], 0, 0, 0);
        }
        __syncthreads();
    }

#pragma unroll
    for (int reg = 0; reg < 4; reg++) {
        int grow = brow + wr0 + (lane >> 4) * 4 + reg;
        if (grow < N) {
#pragma unroll
            for (int ni = 0; ni < 4; ni++) {
                int gcol = wc0 + ni * 16 + (lane & 15);
                int plane = gcol >> 5;
                H[(size_t)plane * N * 32 + (size_t)grow * 32 + (gcol & 31)] =
                    f2bf(acc[ni][reg]);
            }
        }
    }
}

// ---------- gather layer1: 4 column-plane passes; 4 lane-groups x 16 lanes ----------
__global__ __launch_bounds__(256) void k_gather1(const unsigned short* __restrict__ h,
                                                 const int* __restrict__ rowptr,
                                                 const int* __restrict__ col,
                                                 const float* __restrict__ dinv,
                                                 const float* __restrict__ bias,
                                                 unsigned short* __restrict__ out,
                                                 int N, int PB) {
    const int pass = blockIdx.x / PB;
    const int lb = blockIdx.x - pass * PB;
    const int i = (lb * 256 + threadIdx.x) >> 6;
    const int lane = threadIdx.x & 63;
    if (i >= N) return;
    const int g = lane >> 4;                  // edge group 0..3
    const int c2 = (lane & 15) * 2;           // my 2 cols in plane
    const unsigned short* hp = h + (size_t)pass * N * 32 + c2;
    const float di = dinv[i];

    float a0 = 0.f, a1 = 0.f;
    if (g == 0) {                             // self-loop once
        u32 sv = *(const u32*)&hp[(size_t)i * 32];
        float s = di * di;
        a0 = bf_lo(sv) * s; a1 = bf_hi(sv) * s;
    }
    const int beg = rowptr[i], end = rowptr[i + 1];
    for (int p0 = beg; p0 < end; p0 += 64) {
        int idx = p0 + lane;
        bool ok = idx < end;
        int myj = ok ? col[idx] : i;
        float mydj = ok ? dinv[myj] : 0.f;
        const int cnt8 = (min(64, end - p0) + 7) & ~7;
        u32 v0, v1; float w0, w1;
        {
            int j0 = __shfl(myj, g);     w0 = __shfl(mydj, g) * di;
            v0 = *(const u32*)&hp[(size_t)j0 * 32];
            int j1 = __shfl(myj, 4 + g); w1 = __shfl(mydj, 4 + g) * di;
            v1 = *(const u32*)&hp[(size_t)j1 * 32];
        }
        for (int k = 8; k < cnt8; k += 8) {
            int j0 = __shfl(myj, k + g);     float nw0 = __shfl(mydj, k + g) * di;
            u32 nv0 = *(const u32*)&hp[(size_t)j0 * 32];
            int j1 = __shfl(myj, k + 4 + g); float nw1 = __shfl(mydj, k + 4 + g) * di;
            u32 nv1 = *(const u32*)&hp[(size_t)j1 * 32];
            a0 = fmaf(bf_lo(v0), w0, a0); a1 = fmaf(bf_hi(v0), w0, a1);
            a0 = fmaf(bf_lo(v1), w1, a0); a1 = fmaf(bf_hi(v1), w1, a1);
            v0 = nv0; w0 = nw0; v1 = nv1; w1 = nw1;
        }
        a0 = fmaf(bf_lo(v0), w0, a0); a1 = fmaf(bf_hi(v0), w0, a1);
        a0 = fmaf(bf_lo(v1), w1, a0); a1 = fmaf(bf_hi(v1), w1, a1);
    }
    a0 += __shfl_xor(a0, 16); a1 += __shfl_xor(a1, 16);
    a0 += __shfl_xor(a0, 32); a1 += __shfl_xor(a1, 32);
    if (lane < 16) {
        float2 bv = *(const float2*)&bias[pass * 32 + c2];
        u32 w = (u32)f2bf(fmaxf(a0 + bv.x, 0.f)) |
                ((u32)f2bf(fmaxf(a1 + bv.y, 0.f)) << 16);
        *(u32*)&out[(size_t)i * HD1 + pass * 32 + c2] = w;
    }
}

// ---------- GEMM2: agg1[N,128]bf16 @ Wt2[64][128]bf16 -> h2 2 planes [N][32]bf16 ----------
__global__ __launch_bounds__(256) void k_gemm2(const unsigned short* __restrict__ A,
                                               const unsigned short* __restrict__ Wt2,
                                               unsigned short* __restrict__ H, int N) {
    __shared__ unsigned short As[128 * 128];  // swizzled [row][k]
    __shared__ unsigned short Bs[64 * 128];   // swizzled [col][k]
    const int tid = threadIdx.x;
    const int lane = tid & 63;
    const int wid = tid >> 6;
    const int brow = blockIdx.x * 128;
    const int wr0 = wid * 32;

#pragma unroll
    for (int p = 0; p < 8; p++) {
        int chunk = (wid * 8 + p) * 64 + lane;
        int r = chunk >> 4;                 // 16 chunks per 128-elem row
        int kcs = chunk & 15;
        int kc = kcs ^ (r & 7);             // inverse swizzle on source
        const unsigned short* src = &A[(size_t)(brow + r) * HD1 + kc * 8];
        unsigned short* dst = &As[(wid * 8 + p) * 512];
        __builtin_amdgcn_global_load_lds(
            (const __attribute__((address_space(1))) u32*)(const void*)src,
            (__attribute__((address_space(3))) u32*)(void*)dst, 16, 0, 0);
    }
#pragma unroll
    for (int p = 0; p < 4; p++) {
        int chunk = (wid * 4 + p) * 64 + lane;
        int c = chunk >> 4;
        int kcs = chunk & 15;
        int kc = kcs ^ (c & 7);
        const unsigned short* src = &Wt2[(size_t)c * HD1 + kc * 8];
        unsigned short* dst = &Bs[(wid * 4 + p) * 512];
        __builtin_amdgcn_global_load_lds(
            (const __attribute__((address_space(1))) u32*)(const void*)src,
            (__attribute__((address_space(3))) u32*)(void*)dst, 16, 0, 0);
    }
    __syncthreads();

    f32x4 acc[2][4];
#pragma unroll
    for (int i = 0; i < 2; i++)
#pragma unroll
        for (int j = 0; j < 4; j++) acc[i][j] = (f32x4){0.f, 0.f, 0.f, 0.f};

#pragma unroll
    for (int kk = 0; kk < 4; kk++) {
        const int kel = kk * 32 + (lane >> 4) * 8;
        bf16x8 a[2], b[4];
#pragma unroll
        for (int mi = 0; mi < 2; mi++)
            a[mi] = *(const bf16x8*)&As[elem_off128(wr0 + mi * 16 + (lane & 15), kel)];
#pragma unroll
        for (int ni = 0; ni < 4; ni++)
            b[ni] = *(const bf16x8*)&Bs[elem_off128(ni * 16 + (lane & 15), kel)];
#pragma unroll
        for (int mi = 0; mi < 2; mi++)
#pragma unroll
            for (int ni = 0; ni < 4; ni++)
                acc[mi][ni] = __builtin_amdgcn_mfma_f32_16x16x32_bf16(
                    a[mi], b[ni], acc[mi][ni], 0, 0, 0);
    }

#pragma unroll
    for (int mi = 0; mi < 2; mi++) {
#pragma unroll
        for (int reg = 0; reg < 4; reg++) {
            int grow = brow + wr0 + mi * 16 + (lane >> 4) * 4 + reg;
            if (grow < N) {
#pragma unroll
                for (int ni = 0; ni < 4; ni++) {
                    int gcol = ni * 16 + (lane & 15);
                    int plane = gcol >> 5;
                    H[(size_t)plane * N * 32 + (size_t)grow * 32 + (gcol & 31)] =
                        f2bf(acc[mi][ni][reg]);
                }
            }
        }
    }
}

// ---------- gather layer2: 2 column-plane passes, f32 out ----------
__global__ __launch_bounds__(256) void k_gather2(const unsigned short* __restrict__ h,
                                                 const int* __restrict__ rowptr,
                                                 const int* __restrict__ col,
                                                 const float* __restrict__ dinv,
                                                 const float* __restrict__ bias,
                                                 float* __restrict__ out,
                                                 int N, int PB) {
    const int pass = blockIdx.x / PB;
    const int lb = blockIdx.x - pass * PB;
    const int i = (lb * 256 + threadIdx.x) >> 6;
    const int lane = threadIdx.x & 63;
    if (i >= N) return;
    const int g = lane >> 4;
    const int c2 = (lane & 15) * 2;
    const unsigned short* hp = h + (size_t)pass * N * 32 + c2;
    const float di = dinv[i];

    float a0 = 0.f, a1 = 0.f;
    if (g == 0) {
        u32 sv = *(const u32*)&hp[(size_t)i * 32];
        float s = di * di;
        a0 = bf_lo(sv) * s; a1 = bf_hi(sv) * s;
    }
    const int beg = rowptr[i], end = rowptr[i + 1];
    for (int p0 = beg; p0 < end; p0 += 64) {
        int idx = p0 + lane;
        bool ok = idx < end;
        int myj = ok ? col[idx] : i;
        float mydj = ok ? dinv[myj] : 0.f;
        const int cnt8 = (min(64, end - p0) + 7) & ~7;
        u32 v0, v1; float w0, w1;
        {
            int j0 = __shfl(myj, g);     w0 = __shfl(mydj, g) * di;
            v0 = *(const u32*)&hp[(size_t)j0 * 32];
            int j1 = __shfl(myj, 4 + g); w1 = __shfl(mydj, 4 + g) * di;
            v1 = *(const u32*)&hp[(size_t)j1 * 32];
        }
        for (int k = 8; k < cnt8; k += 8) {
            int j0 = __shfl(myj, k + g);     float nw0 = __shfl(mydj, k + g) * di;
            u32 nv0 = *(const u32*)&hp[(size_t)j0 * 32];
            int j1 = __shfl(myj, k + 4 + g); float nw1 = __shfl(mydj, k + 4 + g) * di;
            u32 nv1 = *(const u32*)&hp[(size_t)j1 * 32];
            a0 = fmaf(bf_lo(v0), w0, a0); a1 = fmaf(bf_hi(v0), w0, a1);
            a0 = fmaf(bf_lo(v1), w1, a0); a1 = fmaf(bf_hi(v1), w1, a1);
            v0 = nv0; w0 = nw0; v1 = nv1; w1 = nw1;
        }
        a0 = fmaf(bf_lo(v0), w0, a0); a1 = fmaf(bf_hi(v0), w0, a1);
        a0 = fmaf(bf_lo(v1), w1, a0); a1 = fmaf(bf_hi(v1), w1, a1);
    }
    a0 += __shfl_xor(a0, 16); a1 += __shfl_xor(a1, 16);
    a0 += __shfl_xor(a0, 32); a1 += __shfl_xor(a1, 32);
    if (lane < 16) {
        float2 bv = *(const float2*)&bias[pass * 32 + c2];
        float2 r = make_float2(fmaxf(a0 + bv.x, 0.f), fmaxf(a1 + bv.y, 0.f));
        *(float2*)&out[(size_t)i * HD2 + pass * 32 + c2] = r;
    }
}

extern "C" void kernel_launch(void* const* d_in, const int* in_sizes, int n_in,
                              void* d_out, int out_size, void* d_ws, size_t ws_size,
                              hipStream_t stream) {
    const float* x  = (const float*)d_in[0];
    const int*   ei = (const int*)d_in[1];
    const float* W1 = (const float*)d_in[2];
    const float* b1 = (const float*)d_in[3];
    const float* W2 = (const float*)d_in[4];
    const float* b2 = (const float*)d_in[5];
    float* out = (float*)d_out;

    const int N = in_sizes[0] / IN_DIM;     // 50000
    const int E = in_sizes[1] / 2;          // 800000
    const int* src = ei;
    const int* dst = ei + E;

    // workspace layout (256B aligned)
    char* w = (char*)d_ws;
    size_t off = 0;
    auto alloc = [&](size_t bytes) -> void* {
        void* p = w + off;
        off = (off + bytes + 255) & ~(size_t)255;
        return p;
    };
    int*   deg    = (int*)alloc((size_t)N * 4);
    int*   rank   = (int*)alloc((size_t)E * 4);
    int*   rowptr = (int*)alloc((size_t)(N + 1) * 4);
    int*   bsum   = (int*)alloc(1024 * 4);
    int*   col    = (int*)alloc((size_t)E * 4);
    float* dinv   = (float*)alloc((size_t)N * 4);
    unsigned short* Wt  = (unsigned short*)alloc((size_t)IN_DIM * HD1 * 2);
    unsigned short* Wt2 = (unsigned short*)alloc((size_t)HD2 * HD1 * 2);
    unsigned short* h1  = (unsigned short*)alloc((size_t)N * HD1 * 2);          // 4 planes [N][32]
    unsigned short* agg1= (unsigned short*)alloc((size_t)(N + 128) * HD1 * 2);  // bf16, padded
    unsigned short* h2  = h1;  // 2 planes [N][32]; h1 dead after gather1

    const int nb = (N + 255) / 256;          // 196 <= 256 (k_scan_final assumption)
    const int eb = (E + 255) / 256;
    const int gemmBlocks = (N + 31) / 32;    // 1563
    const int fillBlocks = 512;
    const int PB = (N * 64 + 255) / 256;     // node-wave blocks per pass (12500)

    k_zero<<<nb, 256, 0, stream>>>(deg, N);
    k_prep<<<eb, 256, 0, stream>>>(dst, E, deg, rank, W1, Wt, W2, Wt2);
    k_dinv_bsum<<<nb, 256, 0, stream>>>(deg, N, dinv, bsum);
    k_scan_final<<<nb, 256, 0, stream>>>(deg, N, bsum, nb, rowptr);

    k_mega<<<gemmBlocks + fillBlocks, 256, 0, stream>>>(
        x, Wt, h1, N, gemmBlocks, src, dst, E, rowptr, rank, col);

    k_gather1<<<4 * PB, 256, 0, stream>>>(h1, rowptr, col, dinv, b1, agg1, N, PB);
    k_gemm2<<<(N + 127) / 128, 256, 0, stream>>>(agg1, Wt2, h2, N);
    k_gather2<<<2 * PB, 256, 0, stream>>>(h2, rowptr, col, dinv, b2, out, N, PB);
}

// Round 19
// 145.075 us; speedup vs baseline: 1.4074x; 1.4074x over previous
//
#include <hip/hip_runtime.h>

// 2-layer GCN: h = relu(Anorm @ (x@W1) + b1); out = relu(Anorm @ (h@W2) + b2)
// Round 19: revert to R16 (best, 145.2us) + LDS-repack epilogues in mega/gemm2:
// C-writes become coalesced uint4 row stores (kills the 2.6x partial-sector
// write amplification seen as WRITE_SIZE 41.8MB vs 16MB output). Bitwise same.

constexpr int IN_DIM = 512;
constexpr int HD1 = 128;
constexpr int HD2 = 64;

typedef __attribute__((ext_vector_type(8))) short bf16x8;
typedef __attribute__((ext_vector_type(8))) unsigned short u16x8;
typedef __attribute__((ext_vector_type(4))) float f32x4;
typedef unsigned int u32;

__device__ inline unsigned short f2bf(float f) {
    u32 u = __builtin_bit_cast(u32, f);
    return (unsigned short)((u + 0x7fffu + ((u >> 16) & 1u)) >> 16);
}
__device__ inline float bf_lo(u32 v) { return __builtin_bit_cast(float, v << 16); }
__device__ inline float bf_hi(u32 v) { return __builtin_bit_cast(float, v & 0xffff0000u); }

// swizzled LDS element offset, [row][64] bf16 tiles
__device__ inline int elem_off(int row, int k) {
    return (row << 6) + (k ^ ((row & 7) << 3));
}
// swizzled LDS element offset, [row][128] bf16 tiles (gemm2)
__device__ inline int elem_off128(int row, int k) {
    return (row << 7) + (k ^ ((row & 7) << 3));
}

// ---------- zero deg ----------
__global__ __launch_bounds__(256) void k_zero(int* __restrict__ deg, int N) {
    int i = blockIdx.x * 256 + threadIdx.x;
    if (i < N) deg[i] = 0;
}

// ---------- fused prep: deg atomics (rank captured) + W1^T bf16 + W2^T bf16 ----------
__global__ __launch_bounds__(256) void k_prep(const int* __restrict__ dst, int E,
                                              int* __restrict__ deg,
                                              int* __restrict__ rank,
                                              const float* __restrict__ W1,
                                              unsigned short* __restrict__ Wt,
                                              const float* __restrict__ W2,
                                              unsigned short* __restrict__ Wt2) {
    int id = blockIdx.x * 256 + threadIdx.x;
    if (id < E) rank[id] = atomicAdd(&deg[dst[id]], 1);
    if (id < IN_DIM * HD1) {                    // 65536: W1^T
        int n = id >> 9, k = id & 511;
        Wt[id] = f2bf(W1[k * HD1 + n]);
    }
    if (id < HD1 * HD2) {                       // 8192: W2^T
        int n = id >> 7, k = id & 127;
        Wt2[id] = f2bf(W2[k * HD2 + n]);
    }
}

// ---------- dinv + per-block degree sums (fused) ----------
__global__ __launch_bounds__(256) void k_dinv_bsum(const int* __restrict__ deg, int N,
                                                   float* __restrict__ dinv,
                                                   int* __restrict__ bsum) {
    __shared__ int s[256];
    int t = threadIdx.x;
    int i = blockIdx.x * 256 + t;
    int d = (i < N) ? deg[i] : 0;
    if (i < N) dinv[i] = rsqrtf((float)(d + 1));  // +1 = self loop
    s[t] = d;
    __syncthreads();
    for (int st = 128; st > 0; st >>= 1) {
        if (t < st) s[t] += s[t + st];
        __syncthreads();
    }
    if (t == 0) bsum[blockIdx.x] = s[0];
}

// ---------- scan_final with fused bsum scan (nb <= 256) ----------
__global__ __launch_bounds__(256) void k_scan_final(const int* __restrict__ deg, int N,
                                                    const int* __restrict__ bsum, int nb,
                                                    int* __restrict__ rowptr) {
    __shared__ int sb[256];
    __shared__ int s[256];
    int t = threadIdx.x;
    sb[t] = (t < nb) ? bsum[t] : 0;
    __syncthreads();
    for (int off = 1; off < 256; off <<= 1) {
        int v = (t >= off) ? sb[t - off] : 0;
        __syncthreads();
        sb[t] += v;
        __syncthreads();
    }
    int base = (blockIdx.x == 0) ? 0 : sb[blockIdx.x - 1];

    int i = blockIdx.x * 256 + t;
    int v = (i < N) ? deg[i] : 0;
    s[t] = v;
    __syncthreads();
    for (int off = 1; off < 256; off <<= 1) {
        int u = (t >= off) ? s[t - off] : 0;
        __syncthreads();
        s[t] += u;
        __syncthreads();
    }
    int incl = s[t] + base;
    if (i < N) rowptr[i] = incl - v;
    if (i == N - 1) rowptr[N] = incl;
}

// ---------- MEGA: blocks [0,gemmBlocks) = gemm1 (32-row tiles); rest = fill ----------
__global__ __launch_bounds__(256) void k_mega(const float* __restrict__ X,
                                              const unsigned short* __restrict__ Wt,
                                              unsigned short* __restrict__ H, int N,
                                              int gemmBlocks,
                                              const int* __restrict__ src,
                                              const int* __restrict__ dst, int E,
                                              const int* __restrict__ rowptr,
                                              const int* __restrict__ rank,
                                              int* __restrict__ col) {
    __shared__ unsigned short smem[32 * 64 + 128 * 64];  // 20 KB: As | Bs
    unsigned short* As = smem;                // x tile, swizzled [row][k], 4 KB
    unsigned short* Bs = smem + 32 * 64;      // W tile, swizzled [col][k], 16 KB

    if (blockIdx.x >= gemmBlocks) {
        // ---- CSR fill, atomic-free ----
        const int T = (gridDim.x - gemmBlocks) * 256;
        for (int e = (blockIdx.x - gemmBlocks) * 256 + threadIdx.x; e < E; e += T) {
            int d = dst[e];
            col[rowptr[d] + rank[e]] = src[e];
        }
        return;
    }

    // ---------------- GEMM1: 32 rows x 128 cols per block ----------------
    const int tid = threadIdx.x;
    const int lane = tid & 63;
    const int wid = tid >> 6;
    const int brow = blockIdx.x * 32;
    const int wr0 = (wid >> 1) * 16;          // wave rows: 0 or 16
    const int wc0 = (wid & 1) * 64;           // wave cols: 0 or 64
    const bool full = (brow + 32 <= N);

    f32x4 acc[4];
#pragma unroll
    for (int j = 0; j < 4; j++) acc[j] = (f32x4){0.f, 0.f, 0.f, 0.f};

    for (int kt = 0; kt < IN_DIM / 64; kt++) {
        const int k0 = kt * 64;
        // ---- issue B: global_load_lds, pre-swizzled source ----
#pragma unroll
        for (int p = 0; p < 4; p++) {
            int chunk = (wid * 4 + p) * 64 + lane;  // 16B chunk id
            int n = chunk >> 3;
            int kcs = chunk & 7;
            int kc = kcs ^ (n & 7);                 // inverse swizzle on source
            const unsigned short* srcp = &Wt[(size_t)n * IN_DIM + k0 + kc * 8];
            unsigned short* dstp = &Bs[(wid * 4 + p) * 512];
            __builtin_amdgcn_global_load_lds(
                (const __attribute__((address_space(1))) u32*)(const void*)srcp,
                (__attribute__((address_space(3))) u32*)(void*)dstp, 16, 0, 0);
        }
        // ---- stage A: 32 rows x 64 k, one 8-elem chunk per thread ----
        {
            int r = tid >> 3;
            int kc = tid & 7;
            const float* xp = &X[(size_t)(brow + r) * IN_DIM + k0 + kc * 8];
            float4 v0, v1;
            if (full || (brow + r) < N) {
                v0 = *(const float4*)xp;
                v1 = *(const float4*)(xp + 4);
            } else {
                v0 = make_float4(0.f, 0.f, 0.f, 0.f); v1 = v0;
            }
            u16x8 w;
            w[0] = f2bf(v0.x); w[1] = f2bf(v0.y); w[2] = f2bf(v0.z); w[3] = f2bf(v0.w);
            w[4] = f2bf(v1.x); w[5] = f2bf(v1.y); w[6] = f2bf(v1.z); w[7] = f2bf(v1.w);
            *(u16x8*)&As[elem_off(r, kc * 8)] = w;
        }
        __syncthreads();

#pragma unroll
        for (int kk = 0; kk < 2; kk++) {
            const int kel = kk * 32 + (lane >> 4) * 8;
            bf16x8 a = *(const bf16x8*)&As[elem_off(wr0 + (lane & 15), kel)];
            bf16x8 b[4];
#pragma unroll
            for (int ni = 0; ni < 4; ni++)
                b[ni] = *(const bf16x8*)&Bs[elem_off(wc0 + ni * 16 + (lane & 15), kel)];
#pragma unroll
            for (int ni = 0; ni < 4; ni++)
                acc[ni] = __builtin_amdgcn_mfma_f32_16x16x32_bf16(a, b[ni], acc[ni], 0, 0, 0);
        }
        __syncthreads();
    }

    // ---- epilogue: repack via LDS (aliases dead As/Bs), coalesced uint4 stores ----
    unsigned short* Cs = smem;                // 32 rows x 128 cols bf16 = 8 KB
#pragma unroll
    for (int reg = 0; reg < 4; reg++) {
        int r = wr0 + (lane >> 4) * 4 + reg;
#pragma unroll
        for (int ni = 0; ni < 4; ni++) {
            int c = wc0 + ni * 16 + (lane & 15);
            Cs[r * 128 + c] = f2bf(acc[ni][reg]);
        }
    }
    __syncthreads();
#pragma unroll
    for (int p = 0; p < 2; p++) {
        int idx = tid + p * 256;              // 512 chunks of 16B
        int r = idx >> 4;
        int ch = idx & 15;
        int grow = brow + r;
        if (grow < N) {
            uint4 v = *(const uint4*)&Cs[r * 128 + ch * 8];
            *(uint4*)&H[(size_t)grow * HD1 + ch * 8] = v;
        }
    }
}

// ---------- gather layer1: paired half-wave edges, weights from L2-resident dinv ----------
__global__ __launch_bounds__(256) void k_gather1(const unsigned short* __restrict__ h,
                                                 const int* __restrict__ rowptr,
                                                 const int* __restrict__ col,
                                                 const float* __restrict__ dinv,
                                                 const float* __restrict__ bias,
                                                 unsigned short* __restrict__ out, int N) {
    const int i = (blockIdx.x * 256 + threadIdx.x) >> 6;
    const int lane = threadIdx.x & 63;
    if (i >= N) return;
    const int half = lane >> 5;
    const int c4 = (lane & 31) * 4;           // my 4 columns
    const float di = dinv[i];
    const unsigned short* hc = h + c4;

    float a0 = 0.f, a1 = 0.f, a2 = 0.f, a3 = 0.f;
    if (half == 0) {  // self-loop term counted once
        uint2 sv = *(const uint2*)&hc[(size_t)i * HD1];
        float s = di * di;
        a0 = bf_lo(sv.x) * s; a1 = bf_hi(sv.x) * s;
        a2 = bf_lo(sv.y) * s; a3 = bf_hi(sv.y) * s;
    }
    const int beg = rowptr[i], end = rowptr[i + 1];
    for (int p0 = beg; p0 < end; p0 += 64) {
        int idx = p0 + lane;
        bool okl = idx < end;
        int myj = okl ? col[idx] : i;
        float mydj = okl ? dinv[myj] : 0.f;   // dinv: 200KB, L2-resident
        const int cnt8 = (min(64, end - p0) + 7) & ~7;
        uint2 v[4]; float wv[4];
#pragma unroll
        for (int q = 0; q < 4; q++) {          // prologue: edges 0..7
            int e = 2 * q + half;
            int j = __shfl(myj, e);
            wv[q] = __shfl(mydj, e) * di;
            v[q] = *(const uint2*)&hc[(size_t)j * HD1];
        }
        for (int k = 8; k < cnt8; k += 8) {
            uint2 nv[4]; float nw[4];
#pragma unroll
            for (int q = 0; q < 4; q++) {      // issue next 8 gathers first
                int e = k + 2 * q + half;
                int j = __shfl(myj, e);
                nw[q] = __shfl(mydj, e) * di;
                nv[q] = *(const uint2*)&hc[(size_t)j * HD1];
            }
#pragma unroll
            for (int q = 0; q < 4; q++) {      // consume previous 8
                a0 = fmaf(bf_lo(v[q].x), wv[q], a0);
                a1 = fmaf(bf_hi(v[q].x), wv[q], a1);
                a2 = fmaf(bf_lo(v[q].y), wv[q], a2);
                a3 = fmaf(bf_hi(v[q].y), wv[q], a3);
            }
#pragma unroll
            for (int q = 0; q < 4; q++) { v[q] = nv[q]; wv[q] = nw[q]; }
        }
#pragma unroll
        for (int q = 0; q < 4; q++) {
            a0 = fmaf(bf_lo(v[q].x), wv[q], a0);
            a1 = fmaf(bf_hi(v[q].x), wv[q], a1);
            a2 = fmaf(bf_lo(v[q].y), wv[q], a2);
            a3 = fmaf(bf_hi(v[q].y), wv[q], a3);
        }
    }
    a0 += __shfl_xor(a0, 32);
    a1 += __shfl_xor(a1, 32);
    a2 += __shfl_xor(a2, 32);
    a3 += __shfl_xor(a3, 32);
    if (half == 0) {
        float4 bv = *(const float4*)&bias[c4];
        u32 w0 = (u32)f2bf(fmaxf(a0 + bv.x, 0.f)) | ((u32)f2bf(fmaxf(a1 + bv.y, 0.f)) << 16);
        u32 w1 = (u32)f2bf(fmaxf(a2 + bv.z, 0.f)) | ((u32)f2bf(fmaxf(a3 + bv.w, 0.f)) << 16);
        *(uint2*)&out[(size_t)i * HD1 + c4] = make_uint2(w0, w1);
    }
}

// ---------- GEMM2: agg1[N,128]bf16 @ Wt2[64][128]bf16 -> h2 [N,64]bf16, MFMA ----------
__global__ __launch_bounds__(256) void k_gemm2(const unsigned short* __restrict__ A,
                                               const unsigned short* __restrict__ Wt2,
                                               unsigned short* __restrict__ H, int N) {
    __shared__ unsigned short smem[128 * 128 + 64 * 128];  // 48 KB: As | Bs
    unsigned short* As = smem;                // swizzled [row][k]
    unsigned short* Bs = smem + 128 * 128;    // swizzled [col][k]
    const int tid = threadIdx.x;
    const int lane = tid & 63;
    const int wid = tid >> 6;
    const int brow = blockIdx.x * 128;
    const int wr0 = wid * 32;

#pragma unroll
    for (int p = 0; p < 8; p++) {
        int chunk = (wid * 8 + p) * 64 + lane;
        int r = chunk >> 4;                 // 16 chunks per 128-elem row
        int kcs = chunk & 15;
        int kc = kcs ^ (r & 7);             // inverse swizzle on source
        const unsigned short* src = &A[(size_t)(brow + r) * HD1 + kc * 8];
        unsigned short* dst = &As[(wid * 8 + p) * 512];
        __builtin_amdgcn_global_load_lds(
            (const __attribute__((address_space(1))) u32*)(const void*)src,
            (__attribute__((address_space(3))) u32*)(void*)dst, 16, 0, 0);
    }
#pragma unroll
    for (int p = 0; p < 4; p++) {
        int chunk = (wid * 4 + p) * 64 + lane;
        int c = chunk >> 4;
        int kcs = chunk & 15;
        int kc = kcs ^ (c & 7);
        const unsigned short* src = &Wt2[(size_t)c * HD1 + kc * 8];
        unsigned short* dst = &Bs[(wid * 4 + p) * 512];
        __builtin_amdgcn_global_load_lds(
            (const __attribute__((address_space(1))) u32*)(const void*)src,
            (__attribute__((address_space(3))) u32*)(void*)dst, 16, 0, 0);
    }
    __syncthreads();

    f32x4 acc[2][4];
#pragma unroll
    for (int i = 0; i < 2; i++)
#pragma unroll
        for (int j = 0; j < 4; j++) acc[i][j] = (f32x4){0.f, 0.f, 0.f, 0.f};

#pragma unroll
    for (int kk = 0; kk < 4; kk++) {
        const int kel = kk * 32 + (lane >> 4) * 8;
        bf16x8 a[2], b[4];
#pragma unroll
        for (int mi = 0; mi < 2; mi++)
            a[mi] = *(const bf16x8*)&As[elem_off128(wr0 + mi * 16 + (lane & 15), kel)];
#pragma unroll
        for (int ni = 0; ni < 4; ni++)
            b[ni] = *(const bf16x8*)&Bs[elem_off128(ni * 16 + (lane & 15), kel)];
#pragma unroll
        for (int mi = 0; mi < 2; mi++)
#pragma unroll
            for (int ni = 0; ni < 4; ni++)
                acc[mi][ni] = __builtin_amdgcn_mfma_f32_16x16x32_bf16(
                    a[mi], b[ni], acc[mi][ni], 0, 0, 0);
    }

    // ---- epilogue: repack via LDS, coalesced uint4 stores ----
    __syncthreads();                          // all waves done reading As/Bs
    unsigned short* Cs = smem;                // 128 rows x 64 cols bf16 = 16 KB
#pragma unroll
    for (int mi = 0; mi < 2; mi++) {
#pragma unroll
        for (int reg = 0; reg < 4; reg++) {
            int r = wr0 + mi * 16 + (lane >> 4) * 4 + reg;
#pragma unroll
            for (int ni = 0; ni < 4; ni++) {
                int c = ni * 16 + (lane & 15);
                Cs[r * 64 + c] = f2bf(acc[mi][ni][reg]);
            }
        }
    }
    __syncthreads();
#pragma unroll
    for (int p = 0; p < 4; p++) {
        int idx = tid + p * 256;              // 1024 chunks of 16B
        int r = idx >> 3;
        int ch = idx & 7;
        int grow = brow + r;
        if (grow < N) {
            uint4 v = *(const uint4*)&Cs[r * 64 + ch * 8];
            *(uint4*)&H[(size_t)grow * HD2 + ch * 8] = v;
        }
    }
}

// ---------- gather layer2: paired half-wave edges, f32 out ----------
__global__ __launch_bounds__(256) void k_gather2(const unsigned short* __restrict__ h,
                                                 const int* __restrict__ rowptr,
                                                 const int* __restrict__ col,
                                                 const float* __restrict__ dinv,
                                                 const float* __restrict__ bias,
                                                 float* __restrict__ out, int N) {
    const int i = (blockIdx.x * 256 + threadIdx.x) >> 6;
    const int lane = threadIdx.x & 63;
    if (i >= N) return;
    const int half = lane >> 5;
    const int c2 = (lane & 31) * 2;           // my 2 columns
    const float di = dinv[i];
    const unsigned short* hc = h + c2;

    float a0 = 0.f, a1 = 0.f;
    if (half == 0) {
        u32 sv = *(const u32*)&hc[(size_t)i * HD2];
        float s = di * di;
        a0 = bf_lo(sv) * s; a1 = bf_hi(sv) * s;
    }
    const int beg = rowptr[i], end = rowptr[i + 1];
    for (int p0 = beg; p0 < end; p0 += 64) {
        int idx = p0 + lane;
        bool okl = idx < end;
        int myj = okl ? col[idx] : i;
        float mydj = okl ? dinv[myj] : 0.f;
        const int cnt8 = (min(64, end - p0) + 7) & ~7;
        u32 v[4]; float wv[4];
#pragma unroll
        for (int q = 0; q < 4; q++) {
            int e = 2 * q + half;
            int j = __shfl(myj, e);
            wv[q] = __shfl(mydj, e) * di;
            v[q] = *(const u32*)&hc[(size_t)j * HD2];
        }
        for (int k = 8; k < cnt8; k += 8) {
            u32 nv[4]; float nw[4];
#pragma unroll
            for (int q = 0; q < 4; q++) {
                int e = k + 2 * q + half;
                int j = __shfl(myj, e);
                nw[q] = __shfl(mydj, e) * di;
                nv[q] = *(const u32*)&hc[(size_t)j * HD2];
            }
#pragma unroll
            for (int q = 0; q < 4; q++) {
                a0 = fmaf(bf_lo(v[q]), wv[q], a0);
                a1 = fmaf(bf_hi(v[q]), wv[q], a1);
            }
#pragma unroll
            for (int q = 0; q < 4; q++) { v[q] = nv[q]; wv[q] = nw[q]; }
        }
#pragma unroll
        for (int q = 0; q < 4; q++) {
            a0 = fmaf(bf_lo(v[q]), wv[q], a0);
            a1 = fmaf(bf_hi(v[q]), wv[q], a1);
        }
    }
    a0 += __shfl_xor(a0, 32);
    a1 += __shfl_xor(a1, 32);
    if (half == 0) {
        float2 bv = *(const float2*)&bias[c2];
        float2 r = make_float2(fmaxf(a0 + bv.x, 0.f), fmaxf(a1 + bv.y, 0.f));
        *(float2*)&out[(size_t)i * HD2 + c2] = r;
    }
}

extern "C" void kernel_launch(void* const* d_in, const int* in_sizes, int n_in,
                              void* d_out, int out_size, void* d_ws, size_t ws_size,
                              hipStream_t stream) {
    const float* x  = (const float*)d_in[0];
    const int*   ei = (const int*)d_in[1];
    const float* W1 = (const float*)d_in[2];
    const float* b1 = (const float*)d_in[3];
    const float* W2 = (const float*)d_in[4];
    const float* b2 = (const float*)d_in[5];
    float* out = (float*)d_out;

    const int N = in_sizes[0] / IN_DIM;     // 50000
    const int E = in_sizes[1] / 2;          // 800000
    const int* src = ei;
    const int* dst = ei + E;

    // workspace layout (256B aligned)
    char* w = (char*)d_ws;
    size_t off = 0;
    auto alloc = [&](size_t bytes) -> void* {
        void* p = w + off;
        off = (off + bytes + 255) & ~(size_t)255;
        return p;
    };
    int*   deg    = (int*)alloc((size_t)N * 4);
    int*   rank   = (int*)alloc((size_t)E * 4);
    int*   rowptr = (int*)alloc((size_t)(N + 1) * 4);
    int*   bsum   = (int*)alloc(1024 * 4);
    int*   col    = (int*)alloc((size_t)E * 4);
    float* dinv   = (float*)alloc((size_t)N * 4);
    unsigned short* Wt  = (unsigned short*)alloc((size_t)IN_DIM * HD1 * 2);
    unsigned short* Wt2 = (unsigned short*)alloc((size_t)HD2 * HD1 * 2);
    unsigned short* h1  = (unsigned short*)alloc((size_t)N * HD1 * 2);          // bf16
    unsigned short* agg1= (unsigned short*)alloc((size_t)(N + 128) * HD1 * 2);  // bf16, padded
    unsigned short* h2  = h1;  // h1 dead after gather1; N*64*2 <= N*128*2

    const int nb = (N + 255) / 256;          // 196 <= 256 (k_scan_final assumption)
    const int eb = (E + 255) / 256;
    const int gemmBlocks = (N + 31) / 32;    // 1563
    const int fillBlocks = 512;

    k_zero<<<nb, 256, 0, stream>>>(deg, N);
    k_prep<<<eb, 256, 0, stream>>>(dst, E, deg, rank, W1, Wt, W2, Wt2);
    k_dinv_bsum<<<nb, 256, 0, stream>>>(deg, N, dinv, bsum);
    k_scan_final<<<nb, 256, 0, stream>>>(deg, N, bsum, nb, rowptr);

    k_mega<<<gemmBlocks + fillBlocks, 256, 0, stream>>>(
        x, Wt, h1, N, gemmBlocks, src, dst, E, rowptr, rank, col);

    k_gather1<<<(N * 64 + 255) / 256, 256, 0, stream>>>(h1, rowptr, col, dinv, b1, agg1, N);
    k_gemm2<<<(N + 127) / 128, 256, 0, stream>>>(agg1, Wt2, h2, N);
    k_gather2<<<(N * 64 + 255) / 256, 256, 0, stream>>>(h2, rowptr, col, dinv, b2, out, N);
}